// Round 8
// baseline (624.520 us; speedup 1.0000x reference)
//
#include <hip/hip_runtime.h>
#include <math.h>

#define N_NODES 51200
#define N_EDGES 640000
#define N_TYPES 4
#define N_RELS  8
#define N_HEADS 4
#define D_K     32
#define DIM     128
#define NODES_PER_TYPE (N_NODES / N_TYPES)   // 12800
#define EDGES_PER_REL  (N_EDGES / N_RELS)    // 80000
#define HALF_N  (N_NODES / 2)                // 25600
#define INV_SQRT_DK 0.17677669529663687f

typedef __attribute__((ext_vector_type(8))) short bf16x8;
typedef __attribute__((ext_vector_type(4))) float f32x4;

__device__ inline float bf2f(ushort u) {
    union { unsigned u; float f; } x; x.u = ((unsigned)u) << 16; return x.f;
}
__device__ inline ushort f2bf(float f) {
    union { float f; unsigned u; } x; x.f = f;
    unsigned r = x.u + 0x7FFF + ((x.u >> 16) & 1);
    return (ushort)(r >> 16);
}
__device__ inline bf16x8 pack8(ushort4 a, ushort4 b) {
    bf16x8 f;
    f[0]=(short)a.x; f[1]=(short)a.y; f[2]=(short)a.z; f[3]=(short)a.w;
    f[4]=(short)b.x; f[5]=(short)b.y; f[6]=(short)b.z; f[7]=(short)b.w;
    return f;
}
// global-memory fragment (split-half k layout)
__device__ inline bf16x8 ldfrag(const ushort* p) {
    return pack8(*(const ushort4*)p, *(const ushort4*)(p + 16));
}
// LDS fragment from a [rows][128]-ushort tile, XOR-swizzled: col ^ ((row&7)<<3)
__device__ inline bf16x8 ldsfragA(const ushort* S, int row, int c0) {
    const ushort* p0 = S + row * 128 + ((c0     ) ^ ((row & 7) << 3));
    const ushort* p1 = S + row * 128 + ((c0 + 16) ^ ((row & 7) << 3));
    return pack8(*(const ushort4*)p0, *(const ushort4*)p1);
}

__global__ __launch_bounds__(256) void zero_kernel(float* __restrict__ p, int n4) {
    int i = blockIdx.x * blockDim.x + threadIdx.x;
    if (i < n4) ((float4*)p)[i] = make_float4(0.f, 0.f, 0.f, 0.f);
}

__global__ __launch_bounds__(256) void cvt_h(const float* __restrict__ h, ushort* __restrict__ hb) {
    int i = blockIdx.x * 256 + threadIdx.x;
    float4 v = ((const float4*)h)[i];
    ushort4 o; o.x=f2bf(v.x); o.y=f2bf(v.y); o.z=f2bf(v.z); o.w=f2bf(v.w);
    ((ushort4*)hb)[i] = o;
}

// Transpose + bf16-convert weights. WT (ushort): WkT 0 | WqT 65536 | WvT 131072 |
// WaT 196608 (unused now) | WattT 262144 | WmsgT 294912
__global__ __launch_bounds__(256) void prep_weights(
    const float* __restrict__ Wk, const float* __restrict__ Wq,
    const float* __restrict__ Wv, const float* __restrict__ Wa,
    const float* __restrict__ Watt, const float* __restrict__ Wmsg,
    ushort* __restrict__ WT)
{
    int g = blockIdx.x * 256 + threadIdx.x;
    if (g < 262144) {
        int which = g >> 16;
        int rem = g & 65535;
        int t = rem >> 14, idx = rem & 16383;
        int d = idx >> 7, o = idx & 127;
        const float* src = (which==0)?Wk:(which==1)?Wq:(which==2)?Wv:Wa;
        WT[(size_t)which*65536 + t*16384 + o*128 + d] = f2bf(src[t*16384 + d*128 + o]);
    } else {
        int g2 = g - 262144;
        int which = g2 >> 15;
        int rem = g2 & 32767;
        int rh = rem >> 10, idx = rem & 1023;
        int k = idx >> 5, j = idx & 31;
        const float* src = which ? Wmsg : Watt;
        WT[262144 + which*32768 + rh*1024 + j*32 + k] = f2bf(src[rh*1024 + k*32 + j]);
    }
}

// Combined weights: Wc[r][t][o][k] = sg_t * sum_j Wmsg[r][hh(k)][k%32][j] * Wa[t][hh*32+j][o]
__global__ __launch_bounds__(256) void wc_kernel(
    const float* __restrict__ Wmsg, const float* __restrict__ Wa,
    const float* __restrict__ skip, ushort* __restrict__ Wc)
{
    int idx = blockIdx.x * 256 + threadIdx.x;       // [r][t][o][k], 524288 total
    int r = idx >> 16;
    int t = (idx >> 14) & 3;
    int o = (idx >> 7) & 127;
    int k = idx & 127;
    int hh = k >> 5, kk = k & 31;
    const float* wm = Wmsg + (((size_t)r * 4 + hh) * 32 + kk) * 32;
    const float* wa = Wa + (size_t)t * 16384 + (hh * 32) * 128 + o;
    float acc = 0.f;
    #pragma unroll 8
    for (int j = 0; j < 32; ++j) acc = fmaf(wm[j], wa[j * 128], acc);
    float sg = 1.f / (1.f + expf(-skip[t]));
    Wc[idx] = f2bf(acc * sg);
}

// Fused K/Q/V projection: LDS-staged A and W (swizzled), C through LDS.
__global__ __launch_bounds__(256) void proj_fused(
    const ushort* __restrict__ hb, const ushort* __restrict__ WT,
    ushort* __restrict__ kb, ushort* __restrict__ qb, ushort* __restrict__ vb)
{
    __shared__ ushort As[64 * 128];
    __shared__ ushort Ws[128 * 128];
    const int tid = threadIdx.x;
    const int n0 = blockIdx.x * 64;
    const int t  = n0 / NODES_PER_TYPE;
    const int wv = tid >> 6, l = tid & 63;
    const int rc = l & 15, g = l >> 4, kg = g * 4;
    ushort* Cs = Ws;

    #pragma unroll
    for (int rd = 0; rd < 4; ++rd) {
        int f = tid + rd * 256;
        int row = f >> 4, cu = (f & 15) * 8;
        int4 x = *(const int4*)(hb + (size_t)(n0 + row) * DIM + cu);
        *(int4*)(As + row * 128 + (cu ^ ((row & 7) << 3))) = x;
    }
    {
        const ushort* Wsrc = WT + (size_t)t * 16384;
        #pragma unroll
        for (int rd = 0; rd < 8; ++rd) {
            int f = tid + rd * 256;
            int o = f >> 4, cu = (f & 15) * 8;
            int4 x = *(const int4*)(Wsrc + o * 128 + cu);
            *(int4*)(Ws + o * 128 + (cu ^ ((o & 7) << 3))) = x;
        }
    }
    __syncthreads();

    const int arow = wv * 16 + rc;
    bf16x8 af[4];
    #pragma unroll
    for (int kt = 0; kt < 4; ++kt) af[kt] = ldsfragA(As, arow, kt * 32 + kg);

    for (int which = 0; which < 3; ++which) {
        ushort* outp = (which == 0) ? kb : (which == 1) ? qb : vb;

        f32x4 acc[8];
        #pragma unroll
        for (int ct = 0; ct < 8; ++ct) {
            acc[ct][0]=0.f; acc[ct][1]=0.f; acc[ct][2]=0.f; acc[ct][3]=0.f;
            const int orow = ct * 16 + rc;
            #pragma unroll
            for (int kt = 0; kt < 4; ++kt)
                acc[ct] = __builtin_amdgcn_mfma_f32_16x16x32_bf16(
                    af[kt], ldsfragA(Ws, orow, kt * 32 + kg), acc[ct], 0, 0, 0);
        }
        __syncthreads();

        #pragma unroll
        for (int ct = 0; ct < 8; ++ct)
            #pragma unroll
            for (int i = 0; i < 4; ++i)
                Cs[(wv * 16 + g * 4 + i) * 136 + ct * 16 + rc] = f2bf(acc[ct][i]);
        __syncthreads();

        #pragma unroll
        for (int rd = 0; rd < 4; ++rd) {
            int f = tid + rd * 256;
            int row = f >> 4, cu = (f & 15) * 8;
            int4 x = *(const int4*)(Cs + row * 136 + cu);
            *(int4*)(outp + (size_t)(n0 + row) * DIM + cu) = x;
        }

        if (which < 2) {
            __syncthreads();
            const ushort* Wsrc = WT + (size_t)(which + 1) * 65536 + t * 16384;
            #pragma unroll
            for (int rd = 0; rd < 8; ++rd) {
                int f = tid + rd * 256;
                int o = f >> 4, cu = (f & 15) * 8;
                int4 x = *(const int4*)(Wsrc + o * 128 + cu);
                *(int4*)(Ws + o * 128 + (cu ^ ((o & 7) << 3))) = x;
            }
            __syncthreads();
        }
    }
}

// Per-relation q-transform (block-diag heads), LDS-staged
__global__ __launch_bounds__(256) void trans_fused(
    const ushort* __restrict__ qb, const ushort* __restrict__ Wsrc,
    ushort* __restrict__ tfb)
{
    __shared__ ushort As[64 * 128];
    __shared__ ushort Ws[4096];
    __shared__ ushort Cs[64 * 136];
    const int tid = threadIdx.x;
    const int n0 = blockIdx.x * 64;
    const int wv = tid >> 6, l = tid & 63;
    const int rc = l & 15, g = l >> 4, kg = g * 4;

    #pragma unroll
    for (int rd = 0; rd < 4; ++rd) {
        int f = tid + rd * 256;
        int row = f >> 4, cu = (f & 15) * 8;
        int4 x = *(const int4*)(qb + (size_t)(n0 + row) * DIM + cu);
        *(int4*)(As + row * 128 + (cu ^ ((row & 7) << 3))) = x;
    }
    #pragma unroll
    for (int rd = 0; rd < 4; ++rd) {
        int f = tid + rd * 256;
        int idx = f * 4;
        ushort4 x = *(const ushort4*)(Wsrc + idx);
        *(ushort4*)(Ws + (idx ^ (((idx >> 5) & 7) << 2))) = x;
    }
    __syncthreads();

    const int arow = wv * 16 + rc;
    bf16x8 af[4];
    #pragma unroll
    for (int hh = 0; hh < 4; ++hh) af[hh] = ldsfragA(As, arow, hh * 32 + kg);

    #pragma unroll
    for (int ct = 0; ct < 8; ++ct) {
        const int hh = ct >> 1, jb = (ct & 1) * 16;
        const int j = jb + rc;
        const int w0 = hh * 1024 + j * 32 + kg;
        bf16x8 bf = pack8(*(const ushort4*)(Ws + ( w0        ^ ((j & 7) << 2))),
                          *(const ushort4*)(Ws + ((w0 + 16)  ^ ((j & 7) << 2))));
        f32x4 acc = {0.f, 0.f, 0.f, 0.f};
        acc = __builtin_amdgcn_mfma_f32_16x16x32_bf16(af[hh], bf, acc, 0, 0, 0);
        const int col = hh * 32 + jb + rc;
        #pragma unroll
        for (int i = 0; i < 4; ++i)
            Cs[(wv * 16 + g * 4 + i) * 136 + col] = f2bf(acc[i]);
    }
    __syncthreads();

    #pragma unroll
    for (int rd = 0; rd < 4; ++rd) {
        int f = tid + rd * 256;
        int row = f >> 4, cu = (f & 15) * 8;
        int4 x = *(const int4*)(Cs + row * 136 + cu);
        *(int4*)(tfb + (size_t)(n0 + row) * DIM + cu) = x;
    }
}

// Edge score in CSR order
__global__ __launch_bounds__(256) void score_sorted(
    const ushort* __restrict__ tfb, const ushort* __restrict__ kb,
    const float* __restrict__ pri,
    const int* __restrict__ srcS, const int* __restrict__ dstS,
    float* __restrict__ evals, int p0, int r)
{
    const int tid = threadIdx.x;
    const int lane = tid & 31;
    const int hh = lane >> 3;
    const int eslot = tid >> 5;
    const float prih = pri[r * N_HEADS + hh] * INV_SQRT_DK;
    int p = p0 + blockIdx.x * 32 + eslot;
    #pragma unroll
    for (int it = 0; it < 4; ++it, p += 8) {
        const int src = srcS[p];
        const int dst = dstS[p];
        ushort4 ua = *(const ushort4*)(tfb + (size_t)dst * DIM + lane * 4);
        ushort4 ub = *(const ushort4*)(kb  + (size_t)src * DIM + lane * 4);
        float s = bf2f(ua.x)*bf2f(ub.x) + bf2f(ua.y)*bf2f(ub.y)
                + bf2f(ua.z)*bf2f(ub.z) + bf2f(ua.w)*bf2f(ub.w);
        s += __shfl_xor(s, 1);
        s += __shfl_xor(s, 2);
        s += __shfl_xor(s, 4);
        if ((lane & 7) == 0)
            evals[(size_t)p * N_HEADS + hh] = expf(s * prih);
    }
}

// ---------------- CSR build over (rel, dst) buckets ----------------

__global__ __launch_bounds__(256) void hist_kernel(
    const int* __restrict__ col, int* __restrict__ cnt)
{
    int e = blockIdx.x * 256 + threadIdx.x;
    int r = (unsigned)e / EDGES_PER_REL;
    atomicAdd(&cnt[r * N_NODES + col[e]], 1);
}

__global__ __launch_bounds__(256) void scan1_kernel(
    const int* __restrict__ cnt, int* __restrict__ off, int* __restrict__ bsum)
{
    __shared__ int s[256];
    int g = blockIdx.x * 256 + threadIdx.x;
    int v = cnt[g];
    s[threadIdx.x] = v;
    __syncthreads();
    #pragma unroll
    for (int d = 1; d < 256; d <<= 1) {
        int t = (threadIdx.x >= d) ? s[threadIdx.x - d] : 0;
        __syncthreads();
        s[threadIdx.x] += t;
        __syncthreads();
    }
    off[g] = s[threadIdx.x] - v;
    if (threadIdx.x == 255) bsum[blockIdx.x] = s[255];
}

__global__ __launch_bounds__(256) void scan2_kernel(int* __restrict__ bsum, int nb)
{
    __shared__ int s[256];
    __shared__ int carry;
    const int tid = threadIdx.x;
    if (tid == 0) carry = 0;
    __syncthreads();
    for (int base = 0; base < nb; base += 256) {
        int i = base + tid;
        int v = (i < nb) ? bsum[i] : 0;
        s[tid] = v;
        __syncthreads();
        #pragma unroll
        for (int d = 1; d < 256; d <<= 1) {
            int t = (tid >= d) ? s[tid - d] : 0;
            __syncthreads();
            s[tid] += t;
            __syncthreads();
        }
        int incl = s[tid];
        if (i < nb) bsum[i] = carry + incl - v;
        __syncthreads();
        if (tid == 255) carry += incl;
        __syncthreads();
    }
}

__global__ __launch_bounds__(256) void scan3_kernel(
    int* __restrict__ off, const int* __restrict__ bsum, int* __restrict__ cursor)
{
    int g = blockIdx.x * 256 + threadIdx.x;
    int o = off[g] + bsum[blockIdx.x];
    off[g] = o;
    cursor[g] = o;
}

__global__ __launch_bounds__(256) void scatter_kernel(
    const int* __restrict__ row, const int* __restrict__ col,
    int* __restrict__ cursor, int* __restrict__ srcS, int* __restrict__ dstS)
{
    int e = blockIdx.x * 256 + threadIdx.x;
    int r = (unsigned)e / EDGES_PER_REL;
    int c = col[e];
    int pos = atomicAdd(&cursor[r * N_NODES + c], 1);
    srcS[pos] = row[e];
    dstS[pos] = c;
}

__global__ __launch_bounds__(256) void denom_pull(
    const int* __restrict__ off, const int* __restrict__ cnt,
    const float* __restrict__ evals, float* __restrict__ den)
{
    int g = blockIdx.x * 256 + threadIdx.x;
    int n = g >> 2, hh = g & 3;
    float s = 0.f;
    #pragma unroll
    for (int r = 0; r < N_RELS; ++r) {
        int b = off[r * N_NODES + n];
        int m = cnt[r * N_NODES + n];
        for (int i = 0; i < m; ++i)
            s += evals[(size_t)(b + i) * 4 + hh];
    }
    den[g] = s;
}

// All-8-relation normalized v pull for one node half.
// Yh[r] half-arrays: r<4 in YA, r>=4 in YB (each HALF_N*128 ushorts).
__global__ __launch_bounds__(256) void ypull8(
    const ushort* __restrict__ vb,
    const int* __restrict__ srcS,
    const int* __restrict__ off, const int* __restrict__ cnt,
    const float* __restrict__ evals, const float* __restrict__ den,
    ushort* __restrict__ YA, ushort* __restrict__ YB, int hbase)
{
    const int tid = threadIdx.x;
    const int n = hbase + blockIdx.x * 4 + (tid >> 6);
    const int lane = tid & 63;            // d-pair index
    const int hh = lane >> 4;
    const float rden = 1.f / (den[(size_t)n * 4 + hh] + 1e-16f);
    const uint* vb2 = (const uint*)vb;
    const size_t yrow = ((size_t)(n - hbase) << 6) + lane;
    #pragma unroll
    for (int r = 0; r < N_RELS; ++r) {
        const int b = off[r * N_NODES + n];
        const int m = cnt[r * N_NODES + n];
        float ax = 0.f, ay = 0.f;
        for (int i = 0; i < m; ++i) {
            const int p = b + i;
            const float ev = evals[(size_t)p * 4 + hh];
            const uint v2 = vb2[((size_t)srcS[p] << 6) + lane];
            ax = fmaf(ev, bf2f((ushort)(v2 & 0xffff)), ax);
            ay = fmaf(ev, bf2f((ushort)(v2 >> 16)), ay);
        }
        ushort* Yr = (r < 4) ? (YA + (size_t)r * (HALF_N * DIM))
                             : (YB + (size_t)(r - 4) * (HALF_N * DIM));
        uint o = (uint)f2bf(ax * rden) | ((uint)f2bf(ay * rden) << 16);
        ((uint*)Yr)[yrow] = o;
    }
}

// out[n][colb..colb+63] = sum_r Yh_r[n] @ Wc[r][t] — LDS-staged Y, K=128/rel.
// grid (HALF_N/64, 2): blockIdx.y = column half.
__global__ __launch_bounds__(256) void final_gemm(
    const ushort* __restrict__ YA, const ushort* __restrict__ YB,
    const ushort* __restrict__ Wc, float* __restrict__ outp, int hbase)
{
    __shared__ ushort Ys[64 * 128];     // 16 KB
    __shared__ float Cs[64 * 68];       // 17.4 KB
    const int tid = threadIdx.x;
    const int bx = blockIdx.x;
    const int colb = blockIdx.y * 64;
    const int n0 = hbase + bx * 64;
    const int t = n0 / NODES_PER_TYPE;
    const int wv = tid >> 6, l = tid & 63;
    const int rc = l & 15, g = l >> 4, kg = g * 4;
    const int arow = wv * 16 + rc;

    f32x4 acc[4];
    #pragma unroll
    for (int ct = 0; ct < 4; ++ct) { acc[ct][0]=0.f; acc[ct][1]=0.f; acc[ct][2]=0.f; acc[ct][3]=0.f; }

    for (int r = 0; r < N_RELS; ++r) {
        const ushort* Yr = (r < 4) ? (YA + (size_t)r * (HALF_N * DIM))
                                   : (YB + (size_t)(r - 4) * (HALF_N * DIM));
        __syncthreads();
        #pragma unroll
        for (int rd = 0; rd < 4; ++rd) {
            int f = tid + rd * 256;
            int row = f >> 4, cu = (f & 15) * 8;
            int4 x = *(const int4*)(Yr + (size_t)(bx * 64 + row) * DIM + cu);
            *(int4*)(Ys + row * 128 + (cu ^ ((row & 7) << 3))) = x;
        }
        __syncthreads();

        bf16x8 af[4];
        #pragma unroll
        for (int kt = 0; kt < 4; ++kt) af[kt] = ldsfragA(Ys, arow, kt * 32 + kg);

        const ushort* Wb = Wc + (size_t)(r * 4 + t) * 16384;
        #pragma unroll
        for (int ct = 0; ct < 4; ++ct) {
            const ushort* Bcol = Wb + (size_t)(colb + ct * 16 + rc) * 128 + kg;
            #pragma unroll
            for (int kt = 0; kt < 4; ++kt)
                acc[ct] = __builtin_amdgcn_mfma_f32_16x16x32_bf16(
                    af[kt], ldfrag(Bcol + kt * 32), acc[ct], 0, 0, 0);
        }
    }

    __syncthreads();
    #pragma unroll
    for (int ct = 0; ct < 4; ++ct)
        #pragma unroll
        for (int i = 0; i < 4; ++i)
            Cs[(wv * 16 + g * 4 + i) * 68 + ct * 16 + rc] = acc[ct][i];
    __syncthreads();

    #pragma unroll
    for (int rd = 0; rd < 4; ++rd) {
        int f = tid + rd * 256;
        int row = f >> 4, c4 = (f & 15) * 4;
        float4 x = *(const float4*)(Cs + row * 68 + c4);
        *(float4*)(outp + (size_t)(n0 + row) * DIM + colb + c4) = x;
    }
}

extern "C" void kernel_launch(void* const* d_in, const int* in_sizes, int n_in,
                              void* d_out, int out_size, void* d_ws, size_t ws_size,
                              hipStream_t stream) {
    (void)in_sizes; (void)n_in; (void)out_size; (void)ws_size;
    const float* h    = (const float*)d_in[0];
    const float* Wk   = (const float*)d_in[1];
    const float* Wq   = (const float*)d_in[2];
    const float* Wv   = (const float*)d_in[3];
    const float* Wa   = (const float*)d_in[4];
    const float* Watt = (const float*)d_in[5];
    const float* Wmsg = (const float*)d_in[6];
    const float* pri  = (const float*)d_in[7];
    const float* skip = (const float*)d_in[8];
    const int* row_idx = (const int*)d_in[9];
    const int* col_idx = (const int*)d_in[10];

    float* out = (float*)d_out;
    char*  wsb = (char*)d_ws;

    const size_t BF = (size_t)N_NODES * DIM * 2;   // 13.107 MB per bf16 node array
    // ws map (proven 8*BF = 104.86 MB):
    //  slot0: hb            -> later Yh[0],Yh[1]
    //  slot1: kb            -> later Yh[2],Yh[3]
    //  slot2: vb            (live until last ypull8)
    //  slot3: qb            -> later Yh[4],Yh[5]
    //  slot4: tfb           -> later Yh[6],Yh[7]
    //  slot5-6: staging: evals | den | cnt | off | bsum | cursor | srcS | dstS
    //  slot7: WT (0.66MB) | Wc (1.05MB)
    ushort* hb  = (ushort*)(wsb);
    ushort* kb  = (ushort*)(wsb + BF);
    ushort* vb  = (ushort*)(wsb + 2*BF);
    ushort* qb  = (ushort*)(wsb + 3*BF);
    ushort* tfb = (ushort*)(wsb + 4*BF);
    ushort* YA  = hb;                    // Yh[0..3]: two half-arrays per slot
    ushort* YB  = qb;                    // Yh[4..7]
    ushort* WT  = (ushort*)(wsb + 7*BF);
    ushort* WattT = WT + 262144;
    ushort* Wc  = WT + 327680;

    float* evals = (float*)(wsb + 5*BF);                    // E*4
    float* den   = evals + (size_t)N_EDGES * N_HEADS;       // N*4
    int*   cnt    = (int*)(den + (size_t)N_NODES * N_HEADS);
    int*   off    = cnt + (size_t)N_RELS * N_NODES;
    int*   bsum   = off + (size_t)N_RELS * N_NODES;
    int*   cursor = bsum + 1600;
    int*   srcS   = cursor + (size_t)N_RELS * N_NODES;
    int*   dstS   = srcS + N_EDGES;
    const int NBUCK = N_RELS * N_NODES;

    // 1. weight prep (WT, Wc) + h conversion + zero counts
    prep_weights<<<1280, 256, 0, stream>>>(Wk, Wq, Wv, Wa, Watt, Wmsg, WT);
    wc_kernel<<<2048, 256, 0, stream>>>(Wmsg, Wa, skip, Wc);
    cvt_h<<<(N_NODES * DIM / 4) / 256, 256, 0, stream>>>(h, hb);
    zero_kernel<<<NBUCK / 4 / 256, 256, 0, stream>>>((float*)cnt, NBUCK / 4);
    // 2. fused K/Q/V projection
    proj_fused<<<N_NODES / 64, 256, 0, stream>>>(hb, WT, kb, qb, vb);
    // 3. CSR build + sorted src/dst
    hist_kernel<<<N_EDGES / 256, 256, 0, stream>>>(col_idx, cnt);
    scan1_kernel<<<NBUCK / 256, 256, 0, stream>>>(cnt, off, bsum);
    scan2_kernel<<<1, 256, 0, stream>>>(bsum, NBUCK / 256);
    scan3_kernel<<<NBUCK / 256, 256, 0, stream>>>(off, bsum, cursor);
    scatter_kernel<<<N_EDGES / 256, 256, 0, stream>>>(row_idx, col_idx, cursor, srcS, dstS);
    // 4. score phase
    for (int r = 0; r < N_RELS; ++r) {
        trans_fused<<<N_NODES / 64, 256, 0, stream>>>(qb, WattT + r * 4096, tfb);
        score_sorted<<<EDGES_PER_REL / 32, 256, 0, stream>>>(
            tfb, kb, pri, srcS, dstS, evals, r * EDGES_PER_REL, r);
    }
    // 5. softmax denominators
    denom_pull<<<N_NODES * N_HEADS / 256, 256, 0, stream>>>(off, cnt, evals, den);
    // 6. two node-halves: 8-rel normalized pull + fused (Wmsg·Wa) GEMM -> out
    for (int half = 0; half < 2; ++half) {
        const int hbase = half * HALF_N;
        ypull8<<<HALF_N / 4, 256, 0, stream>>>(vb, srcS, off, cnt, evals, den, YA, YB, hbase);
        final_gemm<<<dim3(HALF_N / 64, 2), 256, 0, stream>>>(YA, YB, Wc, out, hbase);
    }
}